// Round 6
// baseline (440.378 us; speedup 1.0000x reference)
//
#include <hip/hip_runtime.h>
#include <hip/hip_bf16.h>
#include <math.h>

#define NT 16384
#define DIM 2048
#define NE 64
#define TK 8
#define REPS 8   // PROBE: run the K-loop 8x, re-zeroing acc each rep. Last rep's acc is
                 // bit-identical to R4's (outputs exact); earlier reps kept alive via asm sink.
                 // Purpose: lift router_main above the 77us fill cutoff to capture counters,
                 // and split time = epilogue + REPS * gemm_phase.

typedef _Float16 f16_t;
typedef _Float16 half8 __attribute__((ext_vector_type(8)));
typedef float floatx16 __attribute__((ext_vector_type(16)));

union H8U4 { uint4 u; half8 h; };

// ---------------- Prep: W fp32 -> f16 hi/lo in 32x32x16 B-fragment order; block 64 = scalar chain ----------------
__global__ __launch_bounds__(256) void prep_kernel(const float* __restrict__ w,
                                                   const float* __restrict__ expert_loads,
                                                   const float* __restrict__ bias_strength,
                                                   float* __restrict__ ws_bias,
                                                   float* __restrict__ ws_batch,
                                                   f16_t* __restrict__ whi,
                                                   f16_t* __restrict__ wlo,
                                                   float* __restrict__ out_bias_strength) {
    if (blockIdx.x == 64) {
        int e = threadIdx.x;
        if (e < 64) {
            float load = expert_loads[e];
            float s = load;
            #pragma unroll
            for (int off = 32; off >= 1; off >>= 1) s += __shfl_xor(s, off, 64);
            s = fmaxf(s, 1e-8f);
            float q = load / s;
            const float t = 1.0f / 64.0f;
            float kl = t * (logf(t) - logf(fmaxf(q, 1e-8f)));
            #pragma unroll
            for (int off = 32; off >= 1; off >>= 1) kl += __shfl_xor(kl, off, 64);
            float as = 1.0f / (1.0f + expf(-10.0f * kl));
            float nbs = 0.9f * bias_strength[0] + 0.1f * as;
            ws_bias[e] = tanhf((q - t) * 64.0f) * nbs;
            ws_batch[e] = 0.0f;
            if (e == 0) out_bias_strength[0] = nbs;
        }
        return;
    }
    int idx = blockIdx.x * 256 + threadIdx.x;   // (c16, tile, lane)
    int lane = idx & 63;
    int tile = (idx >> 6) & 1;
    int c    = idx >> 7;
    int n = tile * 32 + (lane & 31);
    int k = c * 16 + (lane >> 5) * 8;
    const float* src = w + (size_t)n * DIM + k;
    float4 a = *(const float4*)src;
    float4 b = *(const float4*)(src + 4);
    float v[8] = {a.x, a.y, a.z, a.w, b.x, b.y, b.z, b.w};
    half8 h, l;
    #pragma unroll
    for (int j = 0; j < 8; ++j) {
        f16_t hh = (f16_t)v[j];
        h[j] = hh;
        l[j] = (f16_t)(v[j] - (float)hh);
    }
    *(half8*)(whi + (size_t)idx * 8) = h;
    *(half8*)(wlo + (size_t)idx * 8) = l;
}

// ---------------- Main (PROBE): R4 kernel, K-loop repeated with per-rep acc re-zero ----------------
__global__ __launch_bounds__(512, 4) void router_main(const float* __restrict__ x,
                                                      const f16_t* __restrict__ whi,
                                                      const f16_t* __restrict__ wlo,
                                                      const float* __restrict__ noise,
                                                      const float* __restrict__ ws_bias,
                                                      float* __restrict__ ws_batch,
                                                      float* __restrict__ out) {
    __shared__ float smem[17408];
    __shared__ float bias_sh[64];
    __shared__ float loads_sh[64];

    const int tid = threadIdx.x;
    const int wv  = tid >> 6;
    const int L   = tid & 63;
    const int r   = L & 31;
    const int kh  = L >> 5;
    const int token0 = blockIdx.x * 32;

    if (tid < 64) { bias_sh[tid] = ws_bias[tid]; loads_sh[tid] = 0.0f; }

    unsigned int* xt = (unsigned int*)smem;
    const half8* whi8 = (const half8*)whi;
    const half8* wlo8 = (const half8*)wlo;

    floatx16 acc0, acc1;

    #pragma unroll 1
    for (int rep = 0; rep < REPS; ++rep) {
        // Re-zero: the final rep recomputes R4's exact accumulation -> bit-identical outputs.
        #pragma unroll
        for (int i = 0; i < 16; ++i) { acc0[i] = 0.0f; acc1[i] = 0.0f; }

        #pragma unroll 1
        for (int s = 0; s < 8; ++s) {
            __syncthreads();                       // previous window fully consumed
            #pragma unroll
            for (int q = 0; q < 4; ++q) {
                const int row = wv + q * 8;
                float4 v4 = *(const float4*)(x + (size_t)(token0 + row) * DIM + s * 256 + L * 4);
                uint4 p;
                {
                    f16_t h0 = (f16_t)v4.x, h1 = (f16_t)v4.y, h2 = (f16_t)v4.z, h3 = (f16_t)v4.w;
                    f16_t l0 = (f16_t)(v4.x - (float)h0), l1 = (f16_t)(v4.y - (float)h1);
                    f16_t l2 = (f16_t)(v4.z - (float)h2), l3 = (f16_t)(v4.w - (float)h3);
                    p.x = (unsigned int)__builtin_bit_cast(unsigned short, h0) |
                          ((unsigned int)__builtin_bit_cast(unsigned short, l0) << 16);
                    p.y = (unsigned int)__builtin_bit_cast(unsigned short, h1) |
                          ((unsigned int)__builtin_bit_cast(unsigned short, l1) << 16);
                    p.z = (unsigned int)__builtin_bit_cast(unsigned short, h2) |
                          ((unsigned int)__builtin_bit_cast(unsigned short, l2) << 16);
                    p.w = (unsigned int)__builtin_bit_cast(unsigned short, h3) |
                          ((unsigned int)__builtin_bit_cast(unsigned short, l3) << 16);
                }
                *(uint4*)(xt + row * 260 + L * 4) = p;
            }
            __syncthreads();
            #pragma unroll
            for (int cc = 0; cc < 2; ++cc) {
                const int jw  = wv * 2 + cc;
                const int c16 = s * 16 + jw;
                const unsigned int* fp = xt + r * 260 + jw * 16 + kh * 8;
                uint4 u0 = *(const uint4*)fp;
                uint4 u1 = *(const uint4*)(fp + 4);
                H8U4 ah, al;
                ah.u.x = (u0.x & 0xFFFFu) | (u0.y << 16);
                ah.u.y = (u0.z & 0xFFFFu) | (u0.w << 16);
                ah.u.z = (u1.x & 0xFFFFu) | (u1.y << 16);
                ah.u.w = (u1.z & 0xFFFFu) | (u1.w << 16);
                al.u.x = (u0.x >> 16) | (u0.y & 0xFFFF0000u);
                al.u.y = (u0.z >> 16) | (u0.w & 0xFFFF0000u);
                al.u.z = (u1.x >> 16) | (u1.y & 0xFFFF0000u);
                al.u.w = (u1.z >> 16) | (u1.w & 0xFFFF0000u);
                const int bidx = (c16 * 2) * 64 + L;
                half8 b0h = whi8[bidx];
                half8 b1h = whi8[bidx + 64];
                half8 b0l = wlo8[bidx];
                half8 b1l = wlo8[bidx + 64];
                acc0 = __builtin_amdgcn_mfma_f32_32x32x16_f16(ah.h, b0h, acc0, 0, 0, 0);
                acc1 = __builtin_amdgcn_mfma_f32_32x32x16_f16(ah.h, b1h, acc1, 0, 0, 0);
                acc0 = __builtin_amdgcn_mfma_f32_32x32x16_f16(al.h, b0h, acc0, 0, 0, 0);
                acc1 = __builtin_amdgcn_mfma_f32_32x32x16_f16(al.h, b1h, acc1, 0, 0, 0);
                acc0 = __builtin_amdgcn_mfma_f32_32x32x16_f16(ah.h, b0l, acc0, 0, 0, 0);
                acc1 = __builtin_amdgcn_mfma_f32_32x32x16_f16(ah.h, b1l, acc1, 0, 0, 0);
            }
        }
        // Keep this rep's MFMA chain alive (each MFMA consumes the full acc tuple as C,
        // so pinning elements pins the whole chain). Empty asm -> zero instructions.
        asm volatile("" :: "v"(acc0[0]), "v"(acc0[15]), "v"(acc1[0]), "v"(acc1[15]));
    }

    __syncthreads();

    // C/D layout (verified): col=lane&31, row=(reg&3)+8*(reg>>2)+4*kh
    #pragma unroll
    for (int reg = 0; reg < 16; ++reg) {
        int row = (reg & 3) + 8 * (reg >> 2) + 4 * kh;
        smem[wv * 2176 + row * 68 + r]      = acc0[reg];
        smem[wv * 2176 + row * 68 + 32 + r] = acc1[reg];
    }
    __syncthreads();

    #pragma unroll
    for (int p = 0; p < 4; ++p) {
        int o = tid + p * 512;
        int t = o >> 6, e = o & 63;
        float sum = 0.0f;
        #pragma unroll
        for (int q = 0; q < 8; ++q) sum += smem[q * 2176 + t * 68 + e];
        sum += noise[(size_t)(token0 + t) * NE + e] * 0.01f - bias_sh[e];
        smem[t * 68 + e] = sum;
    }
    __syncthreads();

    if (tid < 32) {
        int t = tid;
        float tv[TK]; int ti_[TK];
        #pragma unroll
        for (int j = 0; j < TK; ++j) { tv[j] = -INFINITY; ti_[j] = 0; }
        for (int e = 0; e < NE; ++e) {
            float v = smem[t * 68 + e]; int id = e;
            #pragma unroll
            for (int j = 0; j < TK; ++j) {
                bool gt = v > tv[j];
                float nv = gt ? v : tv[j];
                int   ni = gt ? id : ti_[j];
                float ov = gt ? tv[j] : v;
                int   oi = gt ? ti_[j] : id;
                tv[j] = nv; ti_[j] = ni; v = ov; id = oi;
            }
        }
        float m = tv[0], ssum = 0.0f, wvv[TK];
        #pragma unroll
        for (int j = 0; j < TK; ++j) { wvv[j] = expf(tv[j] - m); ssum += wvv[j]; }
        float inv = 1.0f / ssum;
        size_t gt_ = (size_t)(token0 + t);
        #pragma unroll
        for (int j = 0; j < TK; ++j) {
            float wgt = wvv[j] * inv;
            out[gt_ * TK + j] = (float)ti_[j];
            out[(size_t)NT * TK + gt_ * TK + j] = wgt;
            atomicAdd(&loads_sh[ti_[j]], wgt);
        }
    }
    __syncthreads();
    if (tid < 64) atomicAdd(&ws_batch[tid], loads_sh[tid]);
}

// ---------------- EMA load update ----------------
__global__ __launch_bounds__(64) void finalize_kernel(const float* __restrict__ expert_loads,
                                                      const float* __restrict__ ws_batch,
                                                      float* __restrict__ out_loads) {
    int e = threadIdx.x;
    out_loads[e] = 0.999f * expert_loads[e] + 0.001f * (ws_batch[e] / (float)NT);
}

extern "C" void kernel_launch(void* const* d_in, const int* in_sizes, int n_in,
                              void* d_out, int out_size, void* d_ws, size_t ws_size,
                              hipStream_t stream) {
    const float* x     = (const float*)d_in[0];  // [16384, 2048]
    const float* rw    = (const float*)d_in[1];  // [64, 2048]
    const float* loads = (const float*)d_in[2];  // [64]
    const float* bs    = (const float*)d_in[3];  // [1]
    const float* noise = (const float*)d_in[4];  // [16384, 64]
    float* out = (float*)d_out;                  // [131072 idx | 131072 w | 64 loads | 1 bias]
    float* ws  = (float*)d_ws;
    float* ws_bias  = ws;
    float* ws_batch = ws + 64;
    f16_t* whi = (f16_t*)(ws + 128);             // 16384 frags x 8 halves = 256 KB
    f16_t* wlo = whi + (size_t)16384 * 8;        // another 256 KB

    prep_kernel<<<65, 256, 0, stream>>>(rw, loads, bs, ws_bias, ws_batch, whi, wlo,
                                        out + (size_t)NT * TK * 2 + NE);
    router_main<<<NT / 32, 512, 0, stream>>>(x, whi, wlo, noise, ws_bias, ws_batch, out);
    finalize_kernel<<<1, 64, 0, stream>>>(loads, ws_batch, out + (size_t)NT * TK * 2);
}

// Round 7
// 241.188 us; speedup vs baseline: 1.8259x; 1.8259x over previous
//
#include <hip/hip_runtime.h>
#include <hip/hip_bf16.h>
#include <math.h>

#define NT 16384
#define DIM 2048
#define NE 64
#define TK 8

typedef _Float16 f16_t;
typedef _Float16 half8 __attribute__((ext_vector_type(8)));
typedef float floatx16 __attribute__((ext_vector_type(16)));

union H8U4 { uint4 u; half8 h; };

// ---------------- Prep: W fp32 -> f16 hi/lo in 32x32x16 B-fragment order; block 64 = scalar chain ----------------
__global__ __launch_bounds__(256) void prep_kernel(const float* __restrict__ w,
                                                   const float* __restrict__ expert_loads,
                                                   const float* __restrict__ bias_strength,
                                                   float* __restrict__ ws_bias,
                                                   f16_t* __restrict__ whi,
                                                   f16_t* __restrict__ wlo,
                                                   float* __restrict__ out_bias_strength) {
    if (blockIdx.x == 64) {
        int e = threadIdx.x;
        if (e < 64) {
            float load = expert_loads[e];
            float s = load;
            #pragma unroll
            for (int off = 32; off >= 1; off >>= 1) s += __shfl_xor(s, off, 64);
            s = fmaxf(s, 1e-8f);
            float q = load / s;
            const float t = 1.0f / 64.0f;
            float kl = t * (logf(t) - logf(fmaxf(q, 1e-8f)));
            #pragma unroll
            for (int off = 32; off >= 1; off >>= 1) kl += __shfl_xor(kl, off, 64);
            float as = 1.0f / (1.0f + expf(-10.0f * kl));
            float nbs = 0.9f * bias_strength[0] + 0.1f * as;
            ws_bias[e] = tanhf((q - t) * 64.0f) * nbs;
            if (e == 0) out_bias_strength[0] = nbs;
        }
        return;
    }
    int idx = blockIdx.x * 256 + threadIdx.x;   // (c16, tile, lane)
    int lane = idx & 63;
    int tile = (idx >> 6) & 1;
    int c    = idx >> 7;
    int n = tile * 32 + (lane & 31);
    int k = c * 16 + (lane >> 5) * 8;
    const float* src = w + (size_t)n * DIM + k;
    float4 a = *(const float4*)src;
    float4 b = *(const float4*)(src + 4);
    float v[8] = {a.x, a.y, a.z, a.w, b.x, b.y, b.z, b.w};
    half8 h, l;
    #pragma unroll
    for (int j = 0; j < 8; ++j) {
        f16_t hh = (f16_t)v[j];
        h[j] = hh;
        l[j] = (f16_t)(v[j] - (float)hh);
    }
    *(half8*)(whi + (size_t)idx * 8) = h;
    *(half8*)(wlo + (size_t)idx * 8) = l;
}

// ---------------- Main: prefetch-pipelined split-f16 MFMA GEMM + wave-parallel top-8 ----------------
// 512 thr = 8 waves = split-K x8. Tile 32 tokens x 64 experts. Grid 512 = 2 blocks/CU.
// K-loop: window s+1's global x-loads are issued between ds_write(s) and barrier2(s) ->
// issue stays one window ahead of the vmcnt(0) barrier drain -> BW-bound, not latency-bound.
// Epilogue: per-block non-atomic load partials (kills 512-deep global atomic chains);
// top-8 via 64-lane argmax butterflies, 8 waves x 4 tokens (all threads busy).
__global__ __launch_bounds__(512, 4) void router_main(const float* __restrict__ x,
                                                      const f16_t* __restrict__ whi,
                                                      const f16_t* __restrict__ wlo,
                                                      const float* __restrict__ noise,
                                                      const float* __restrict__ ws_bias,
                                                      float* __restrict__ ws_part,
                                                      float* __restrict__ out) {
    __shared__ float smem[17408];   // staging 32x260 u32 (33,280B) overlaid by part[8][32][68]
    __shared__ float bias_sh[64];
    __shared__ float loads_sh[64];

    const int tid = threadIdx.x;
    const int wv  = tid >> 6;
    const int L   = tid & 63;
    const int r   = L & 31;
    const int kh  = L >> 5;
    const int token0 = blockIdx.x * 32;

    if (tid < 64) { bias_sh[tid] = ws_bias[tid]; loads_sh[tid] = 0.0f; }

    unsigned int* xt = (unsigned int*)smem;
    const half8* whi8 = (const half8*)whi;
    const half8* wlo8 = (const half8*)wlo;

    floatx16 acc0, acc1;
    #pragma unroll
    for (int i = 0; i < 16; ++i) { acc0[i] = 0.0f; acc1[i] = 0.0f; }

    // preload window 0 (each wave owns rows wv, wv+8, wv+16, wv+24 of the staging step)
    float4 pre[4];
    #pragma unroll
    for (int q = 0; q < 4; ++q)
        pre[q] = *(const float4*)(x + (size_t)(token0 + wv + q * 8) * DIM + L * 4);

    #pragma unroll 1
    for (int s = 0; s < 8; ++s) {
        __syncthreads();                       // previous window fully consumed
        #pragma unroll
        for (int q = 0; q < 4; ++q) {
            const int row = wv + q * 8;
            float4 v4 = pre[q];
            uint4 p;
            {
                f16_t h0 = (f16_t)v4.x, h1 = (f16_t)v4.y, h2 = (f16_t)v4.z, h3 = (f16_t)v4.w;
                f16_t l0 = (f16_t)(v4.x - (float)h0), l1 = (f16_t)(v4.y - (float)h1);
                f16_t l2 = (f16_t)(v4.z - (float)h2), l3 = (f16_t)(v4.w - (float)h3);
                p.x = (unsigned int)__builtin_bit_cast(unsigned short, h0) |
                      ((unsigned int)__builtin_bit_cast(unsigned short, l0) << 16);
                p.y = (unsigned int)__builtin_bit_cast(unsigned short, h1) |
                      ((unsigned int)__builtin_bit_cast(unsigned short, l1) << 16);
                p.z = (unsigned int)__builtin_bit_cast(unsigned short, h2) |
                      ((unsigned int)__builtin_bit_cast(unsigned short, l2) << 16);
                p.w = (unsigned int)__builtin_bit_cast(unsigned short, h3) |
                      ((unsigned int)__builtin_bit_cast(unsigned short, l3) << 16);
            }
            *(uint4*)(xt + row * 260 + L * 4) = p;
        }
        // prefetch next window BEFORE the consume barrier (issue-ahead; s=7 re-reads 7, L1-hit)
        const int sn = (s < 7) ? s + 1 : 7;
        float4 nxt[4];
        #pragma unroll
        for (int q = 0; q < 4; ++q)
            nxt[q] = *(const float4*)(x + (size_t)(token0 + wv + q * 8) * DIM + sn * 256 + L * 4);
        __syncthreads();                       // staged data visible
        #pragma unroll
        for (int cc = 0; cc < 2; ++cc) {
            const int jw  = wv * 2 + cc;
            const int c16 = s * 16 + jw;
            const unsigned int* fp = xt + r * 260 + jw * 16 + kh * 8;
            uint4 u0 = *(const uint4*)fp;
            uint4 u1 = *(const uint4*)(fp + 4);
            H8U4 ah, al;
            ah.u.x = (u0.x & 0xFFFFu) | (u0.y << 16);
            ah.u.y = (u0.z & 0xFFFFu) | (u0.w << 16);
            ah.u.z = (u1.x & 0xFFFFu) | (u1.y << 16);
            ah.u.w = (u1.z & 0xFFFFu) | (u1.w << 16);
            al.u.x = (u0.x >> 16) | (u0.y & 0xFFFF0000u);
            al.u.y = (u0.z >> 16) | (u0.w & 0xFFFF0000u);
            al.u.z = (u1.x >> 16) | (u1.y & 0xFFFF0000u);
            al.u.w = (u1.z >> 16) | (u1.w & 0xFFFF0000u);
            const int bidx = (c16 * 2) * 64 + L;
            half8 b0h = whi8[bidx];
            half8 b1h = whi8[bidx + 64];
            half8 b0l = wlo8[bidx];
            half8 b1l = wlo8[bidx + 64];
            acc0 = __builtin_amdgcn_mfma_f32_32x32x16_f16(ah.h, b0h, acc0, 0, 0, 0);
            acc1 = __builtin_amdgcn_mfma_f32_32x32x16_f16(ah.h, b1h, acc1, 0, 0, 0);
            acc0 = __builtin_amdgcn_mfma_f32_32x32x16_f16(al.h, b0h, acc0, 0, 0, 0);
            acc1 = __builtin_amdgcn_mfma_f32_32x32x16_f16(al.h, b1h, acc1, 0, 0, 0);
            acc0 = __builtin_amdgcn_mfma_f32_32x32x16_f16(ah.h, b0l, acc0, 0, 0, 0);
            acc1 = __builtin_amdgcn_mfma_f32_32x32x16_f16(ah.h, b1l, acc1, 0, 0, 0);
        }
        #pragma unroll
        for (int q = 0; q < 4; ++q) pre[q] = nxt[q];
    }

    __syncthreads();   // all frag reads done; reuse staging region as part[]

    // C/D layout (verified): col=lane&31, row=(reg&3)+8*(reg>>2)+4*kh
    #pragma unroll
    for (int reg = 0; reg < 16; ++reg) {
        int row = (reg & 3) + 8 * (reg >> 2) + 4 * kh;
        smem[wv * 2176 + row * 68 + r]      = acc0[reg];
        smem[wv * 2176 + row * 68 + 32 + r] = acc1[reg];
    }
    __syncthreads();

    // Split-K reduce + noise + bias -> final logits into part[0]  (same order as R4 -> bit-identical)
    #pragma unroll
    for (int p = 0; p < 4; ++p) {
        int o = tid + p * 512;
        int t = o >> 6, e = o & 63;
        float sum = 0.0f;
        #pragma unroll
        for (int q = 0; q < 8; ++q) sum += smem[q * 2176 + t * 68 + e];
        sum += noise[(size_t)(token0 + t) * NE + e] * 0.01f - bias_sh[e];
        smem[t * 68 + e] = sum;
    }
    __syncthreads();

    // Wave-parallel top-8: wave wv handles tokens 4wv..4wv+3. 64-lane argmax butterfly,
    // lower-index tie-break == sequential-scan semantics of R4 (verified pass).
    #pragma unroll 1
    for (int t4 = 0; t4 < 4; ++t4) {
        const int t = wv * 4 + t4;
        float v = smem[t * 68 + L];
        unsigned idx = (unsigned)L;
        float m0 = 0.0f;
        float myv = -INFINITY; unsigned myi = 0;   // lane j<8 captures round j's winner
        #pragma unroll
        for (int j = 0; j < 8; ++j) {
            float bv = v; unsigned bi = idx;
            #pragma unroll
            for (int off = 32; off >= 1; off >>= 1) {
                float    ov = __shfl_xor(bv, off, 64);
                unsigned oi = (unsigned)__shfl_xor((int)bi, off, 64);
                bool take = (ov > bv) || (ov == bv && oi < bi);
                bv = take ? ov : bv;
                bi = take ? oi : bi;
            }
            if (j == 0) m0 = bv;
            if ((int)L == j) { myv = bv; myi = bi; }
            if (idx == bi) v = -INFINITY;          // knock out winner
        }
        float wexp = expf(myv - m0);               // lanes>=8: exp(-inf)=0
        float ssum = wexp;
        ssum += __shfl_xor(ssum, 1, 64);
        ssum += __shfl_xor(ssum, 2, 64);
        ssum += __shfl_xor(ssum, 4, 64);           // sum within each 8-lane group
        if (L < 8) {
            float wgt = wexp * (1.0f / ssum);
            size_t gt_ = (size_t)(token0 + t);
            out[gt_ * TK + L] = (float)myi;
            out[(size_t)NT * TK + gt_ * TK + L] = wgt;
            atomicAdd(&loads_sh[myi], wgt);
        }
    }
    __syncthreads();
    // Non-atomic per-block partial (kills the 512-deep global atomic chains)
    if (tid < 64) ws_part[(size_t)blockIdx.x * 64 + tid] = loads_sh[tid];
}

// ---------------- Finalize: reduce per-block partials + EMA ----------------
__global__ __launch_bounds__(64) void finalize_kernel(const float* __restrict__ expert_loads,
                                                      const float* __restrict__ ws_part,
                                                      float* __restrict__ out_loads) {
    int e = threadIdx.x;
    float s0 = 0, s1 = 0, s2 = 0, s3 = 0, s4 = 0, s5 = 0, s6 = 0, s7 = 0;
    #pragma unroll 1
    for (int b = 0; b < 512; b += 8) {     // 8 independent chains; coalesced 64-lane reads
        s0 += ws_part[(b + 0) * 64 + e];
        s1 += ws_part[(b + 1) * 64 + e];
        s2 += ws_part[(b + 2) * 64 + e];
        s3 += ws_part[(b + 3) * 64 + e];
        s4 += ws_part[(b + 4) * 64 + e];
        s5 += ws_part[(b + 5) * 64 + e];
        s6 += ws_part[(b + 6) * 64 + e];
        s7 += ws_part[(b + 7) * 64 + e];
    }
    float s = ((s0 + s1) + (s2 + s3)) + ((s4 + s5) + (s6 + s7));
    out_loads[e] = 0.999f * expert_loads[e] + 0.001f * (s / (float)NT);
}

extern "C" void kernel_launch(void* const* d_in, const int* in_sizes, int n_in,
                              void* d_out, int out_size, void* d_ws, size_t ws_size,
                              hipStream_t stream) {
    const float* x     = (const float*)d_in[0];  // [16384, 2048]
    const float* rw    = (const float*)d_in[1];  // [64, 2048]
    const float* loads = (const float*)d_in[2];  // [64]
    const float* bs    = (const float*)d_in[3];  // [1]
    const float* noise = (const float*)d_in[4];  // [16384, 64]
    float* out = (float*)d_out;                  // [131072 idx | 131072 w | 64 loads | 1 bias]
    float* ws  = (float*)d_ws;
    float* ws_bias = ws;                         // 64 floats
    float* ws_part = ws + 64;                    // 512 blocks x 64 floats = 128 KB
    f16_t* whi = (f16_t*)(ws + 64 + 512 * 64);   // 256 KB (16B-aligned offset)
    f16_t* wlo = whi + (size_t)16384 * 8;        // 256 KB

    prep_kernel<<<65, 256, 0, stream>>>(rw, loads, bs, ws_bias, whi, wlo,
                                        out + (size_t)NT * TK * 2 + NE);
    router_main<<<NT / 32, 512, 0, stream>>>(x, whi, wlo, noise, ws_bias, ws_part, out);
    finalize_kernel<<<1, 64, 0, stream>>>(loads, ws_part, out + (size_t)NT * TK * 2);
}